// Round 1
// baseline (6153.554 us; speedup 1.0000x reference)
//
#include <hip/hip_runtime.h>
#include <hip/hip_bf16.h>

#define IN_DIM   128
#define NH       8
#define HD       16
#define OUTD     128   // NH*HD
#define QKVD     384   // 3*OUTD

// ---------------------------------------------------------------------------
// Kernel 1: fused QKV projection.  qkv[n][0:128]=Q, [128:256]=K, [256:384]=V
// C = x @ W + b, tiled 64x64, K=128 staged via LDS in chunks of 32.
// ---------------------------------------------------------------------------
__global__ __launch_bounds__(256) void qkv_gemm(
    const float* __restrict__ x,
    const float* __restrict__ Wq, const float* __restrict__ bq,
    const float* __restrict__ Wk, const float* __restrict__ bk,
    const float* __restrict__ Wv, const float* __restrict__ bv,
    float* __restrict__ qkv, int N)
{
    __shared__ float xs[64][33];    // [row][k] padded
    __shared__ float ws[32][65];    // [k][col] padded

    const int tid = threadIdx.x;
    const int tx = tid & 15;        // col direction
    const int ty = tid >> 4;        // row direction

    const int colTile = blockIdx.x;          // 0..5
    const int row0    = blockIdx.y * 64;
    const int mat     = colTile >> 1;        // 0=Q,1=K,2=V
    const int wc0     = (colTile & 1) * 64;  // col offset within matrix

    const float* W = (mat == 0) ? Wq : (mat == 1) ? Wk : Wv;
    const float* B = (mat == 0) ? bq : (mat == 1) ? bk : bv;

    float acc[4][4];
#pragma unroll
    for (int i = 0; i < 4; i++)
#pragma unroll
        for (int j = 0; j < 4; j++) acc[i][j] = 0.f;

    for (int kt = 0; kt < 4; kt++) {
        const int k0 = kt * 32;
        // stage x tile: 64 rows x 32 k  (2048 floats, 8/thread)
        {
            int idx = tid * 8;
            int lr = idx >> 5;          // 0..63
            int lk = idx & 31;          // 0,8,16,24
            int grow = row0 + lr; if (grow > N - 1) grow = N - 1;
            const float* xp = x + (size_t)grow * IN_DIM + k0 + lk;
            float4 a0 = *(const float4*)xp;
            float4 a1 = *(const float4*)(xp + 4);
            xs[lr][lk + 0] = a0.x; xs[lr][lk + 1] = a0.y;
            xs[lr][lk + 2] = a0.z; xs[lr][lk + 3] = a0.w;
            xs[lr][lk + 4] = a1.x; xs[lr][lk + 5] = a1.y;
            xs[lr][lk + 6] = a1.z; xs[lr][lk + 7] = a1.w;
        }
        // stage W tile: 32 k x 64 cols (2048 floats, 8/thread)
        {
            int idx = tid * 8;
            int lk = idx >> 6;          // 0..31
            int lc = idx & 63;          // 0,8,...,56
            const float* wp = W + (size_t)(k0 + lk) * OUTD + wc0 + lc;
            float4 b0 = *(const float4*)wp;
            float4 b1 = *(const float4*)(wp + 4);
            ws[lk][lc + 0] = b0.x; ws[lk][lc + 1] = b0.y;
            ws[lk][lc + 2] = b0.z; ws[lk][lc + 3] = b0.w;
            ws[lk][lc + 4] = b1.x; ws[lk][lc + 5] = b1.y;
            ws[lk][lc + 6] = b1.z; ws[lk][lc + 7] = b1.w;
        }
        __syncthreads();

#pragma unroll
        for (int kk = 0; kk < 32; kk++) {
            float a0 = xs[ty +  0][kk];
            float a1 = xs[ty + 16][kk];
            float a2 = xs[ty + 32][kk];
            float a3 = xs[ty + 48][kk];
            float b0 = ws[kk][tx +  0];
            float b1 = ws[kk][tx + 16];
            float b2 = ws[kk][tx + 32];
            float b3 = ws[kk][tx + 48];
            acc[0][0] += a0 * b0; acc[0][1] += a0 * b1; acc[0][2] += a0 * b2; acc[0][3] += a0 * b3;
            acc[1][0] += a1 * b0; acc[1][1] += a1 * b1; acc[1][2] += a1 * b2; acc[1][3] += a1 * b3;
            acc[2][0] += a2 * b0; acc[2][1] += a2 * b1; acc[2][2] += a2 * b2; acc[2][3] += a2 * b3;
            acc[3][0] += a3 * b0; acc[3][1] += a3 * b1; acc[3][2] += a3 * b2; acc[3][3] += a3 * b3;
        }
        __syncthreads();
    }

#pragma unroll
    for (int i = 0; i < 4; i++) {
        int r = row0 + ty + 16 * i;
        if (r < N) {
#pragma unroll
            for (int j = 0; j < 4; j++) {
                int c = tx + 16 * j;
                qkv[(size_t)r * QKVD + mat * OUTD + wc0 + c] = acc[i][j] + B[wc0 + c];
            }
        }
    }
}

// ---------------------------------------------------------------------------
// Kernel 2: edge attention. One thread per (edge, head).
// score = exp(clip(K[src].Q[dst]/4, -5, 5)); atomic scatter to out (wV) and Z.
// ---------------------------------------------------------------------------
__global__ __launch_bounds__(256) void edge_attn(
    const float* __restrict__ qkv,
    const int*   __restrict__ ei,   // [2][E]
    float* __restrict__ out,        // [N][128] accumulates wV
    float* __restrict__ Z,          // [N][8]
    int E)
{
    int t = blockIdx.x * 256 + threadIdx.x;
    if (t >= E * NH) return;
    int e = t >> 3;
    int h = t & 7;
    int src = ei[e];
    int dst = ei[E + e];

    const float4* qp = (const float4*)(qkv + (size_t)dst * QKVD +            h * HD);
    const float4* kp = (const float4*)(qkv + (size_t)src * QKVD + OUTD    + h * HD);
    const float4* vp = (const float4*)(qkv + (size_t)src * QKVD + 2*OUTD  + h * HD);

    float dot = 0.f;
#pragma unroll
    for (int i = 0; i < 4; i++) {
        float4 k4 = kp[i];
        float4 q4 = qp[i];
        dot += k4.x * q4.x + k4.y * q4.y + k4.z * q4.z + k4.w * q4.w;
    }
    dot *= 0.25f;                       // 1/sqrt(16)
    dot = fminf(fmaxf(dot, -5.f), 5.f);
    float s = __expf(dot);

    float* ob = out + (size_t)dst * OUTD + h * HD;
#pragma unroll
    for (int i = 0; i < 4; i++) {
        float4 v4 = vp[i];
        atomicAdd(ob + 4 * i + 0, v4.x * s);
        atomicAdd(ob + 4 * i + 1, v4.y * s);
        atomicAdd(ob + 4 * i + 2, v4.z * s);
        atomicAdd(ob + 4 * i + 3, v4.w * s);
    }
    atomicAdd(Z + (size_t)dst * NH + h, s);
}

// ---------------------------------------------------------------------------
// Kernel 3: normalize out /= (Z + 1e-6)
// ---------------------------------------------------------------------------
__global__ __launch_bounds__(256) void normalize(
    float* __restrict__ out, const float* __restrict__ Z, int nf4)
{
    int idx = blockIdx.x * 256 + threadIdx.x;
    if (idx >= nf4) return;                 // nf4 = N*32 float4s
    int node = idx >> 5;
    int h = (idx >> 2) & 7;
    float z = Z[node * NH + h] + 1e-6f;
    float4* o4 = (float4*)out;
    float4 v = o4[idx];
    v.x /= z; v.y /= z; v.z /= z; v.w /= z;
    o4[idx] = v;
}

extern "C" void kernel_launch(void* const* d_in, const int* in_sizes, int n_in,
                              void* d_out, int out_size, void* d_ws, size_t ws_size,
                              hipStream_t stream) {
    const float* x  = (const float*)d_in[0];
    const int*   ei = (const int*)d_in[1];
    const float* Wq = (const float*)d_in[4];
    const float* bq = (const float*)d_in[5];
    const float* Wk = (const float*)d_in[6];
    const float* bk = (const float*)d_in[7];
    const float* Wv = (const float*)d_in[8];
    const float* bv = (const float*)d_in[9];
    float* out = (float*)d_out;

    const int N = in_sizes[0] / IN_DIM;     // 100000
    const int E = in_sizes[1] / 2;          // 800000

    float* qkv = (float*)d_ws;                                   // N*384 f32
    float* Z   = (float*)((char*)d_ws + (size_t)N * QKVD * 4);   // N*8 f32

    // zero accumulators (out is re-poisoned 0xAA before every launch)
    hipMemsetAsync(d_out, 0, (size_t)N * OUTD * 4, stream);
    hipMemsetAsync(Z, 0, (size_t)N * NH * 4, stream);

    dim3 ggrid(6, (N + 63) / 64);
    qkv_gemm<<<ggrid, 256, 0, stream>>>(x, Wq, bq, Wk, bk, Wv, bv, qkv, N);

    int nt = E * NH;
    edge_attn<<<(nt + 255) / 256, 256, 0, stream>>>(qkv, ei, out, Z, E);

    int nf4 = N * 32;
    normalize<<<(nf4 + 255) / 256, 256, 0, stream>>>(out, Z, nf4);
}

// Round 2
// 506.689 us; speedup vs baseline: 12.1446x; 12.1446x over previous
//
#include <hip/hip_runtime.h>
#include <hip/hip_bf16.h>

#define IN_DIM   128
#define NH       8
#define HD       16
#define OUTD     128   // NH*HD
#define QKVD     384   // 3*OUTD

// ---------------------------------------------------------------------------
// Kernel 1: fused QKV projection.  qkv[n][0:128]=Q, [128:256]=K, [256:384]=V
// ---------------------------------------------------------------------------
__global__ __launch_bounds__(256) void qkv_gemm(
    const float* __restrict__ x,
    const float* __restrict__ Wq, const float* __restrict__ bq,
    const float* __restrict__ Wk, const float* __restrict__ bk,
    const float* __restrict__ Wv, const float* __restrict__ bv,
    float* __restrict__ qkv, int N)
{
    __shared__ float xs[64][33];    // [row][k] padded
    __shared__ float ws[32][65];    // [k][col] padded

    const int tid = threadIdx.x;
    const int tx = tid & 15;        // col direction
    const int ty = tid >> 4;        // row direction

    const int colTile = blockIdx.x;          // 0..5
    const int row0    = blockIdx.y * 64;
    const int mat     = colTile >> 1;        // 0=Q,1=K,2=V
    const int wc0     = (colTile & 1) * 64;  // col offset within matrix

    const float* W = (mat == 0) ? Wq : (mat == 1) ? Wk : Wv;
    const float* B = (mat == 0) ? bq : (mat == 1) ? bk : bv;

    float acc[4][4];
#pragma unroll
    for (int i = 0; i < 4; i++)
#pragma unroll
        for (int j = 0; j < 4; j++) acc[i][j] = 0.f;

    for (int kt = 0; kt < 4; kt++) {
        const int k0 = kt * 32;
        {
            int idx = tid * 8;
            int lr = idx >> 5;          // 0..63
            int lk = idx & 31;          // 0,8,16,24
            int grow = row0 + lr; if (grow > N - 1) grow = N - 1;
            const float* xp = x + (size_t)grow * IN_DIM + k0 + lk;
            float4 a0 = *(const float4*)xp;
            float4 a1 = *(const float4*)(xp + 4);
            xs[lr][lk + 0] = a0.x; xs[lr][lk + 1] = a0.y;
            xs[lr][lk + 2] = a0.z; xs[lr][lk + 3] = a0.w;
            xs[lr][lk + 4] = a1.x; xs[lr][lk + 5] = a1.y;
            xs[lr][lk + 6] = a1.z; xs[lr][lk + 7] = a1.w;
        }
        {
            int idx = tid * 8;
            int lk = idx >> 6;          // 0..31
            int lc = idx & 63;          // 0,8,...,56
            const float* wp = W + (size_t)(k0 + lk) * OUTD + wc0 + lc;
            float4 b0 = *(const float4*)wp;
            float4 b1 = *(const float4*)(wp + 4);
            ws[lk][lc + 0] = b0.x; ws[lk][lc + 1] = b0.y;
            ws[lk][lc + 2] = b0.z; ws[lk][lc + 3] = b0.w;
            ws[lk][lc + 4] = b1.x; ws[lk][lc + 5] = b1.y;
            ws[lk][lc + 6] = b1.z; ws[lk][lc + 7] = b1.w;
        }
        __syncthreads();

#pragma unroll
        for (int kk = 0; kk < 32; kk++) {
            float a0 = xs[ty +  0][kk];
            float a1 = xs[ty + 16][kk];
            float a2 = xs[ty + 32][kk];
            float a3 = xs[ty + 48][kk];
            float b0 = ws[kk][tx +  0];
            float b1 = ws[kk][tx + 16];
            float b2 = ws[kk][tx + 32];
            float b3 = ws[kk][tx + 48];
            acc[0][0] += a0 * b0; acc[0][1] += a0 * b1; acc[0][2] += a0 * b2; acc[0][3] += a0 * b3;
            acc[1][0] += a1 * b0; acc[1][1] += a1 * b1; acc[1][2] += a1 * b2; acc[1][3] += a1 * b3;
            acc[2][0] += a2 * b0; acc[2][1] += a2 * b1; acc[2][2] += a2 * b2; acc[2][3] += a2 * b3;
            acc[3][0] += a3 * b0; acc[3][1] += a3 * b1; acc[3][2] += a3 * b2; acc[3][3] += a3 * b3;
        }
        __syncthreads();
    }

#pragma unroll
    for (int i = 0; i < 4; i++) {
        int r = row0 + ty + 16 * i;
        if (r < N) {
#pragma unroll
            for (int j = 0; j < 4; j++) {
                int c = tx + 16 * j;
                qkv[(size_t)r * QKVD + mat * OUTD + wc0 + c] = acc[i][j] + B[wc0 + c];
            }
        }
    }
}

// ---------------------------------------------------------------------------
// CSR build: histogram -> block scan -> scatter (counting sort of edges by dst)
// P[] is N ints: deg -> exclusive rowptr (in place) -> mutated to rowptr[n+1]
// ---------------------------------------------------------------------------
__global__ __launch_bounds__(256) void histo(
    const int* __restrict__ ei, int* __restrict__ P, int E)
{
    int e = blockIdx.x * 256 + threadIdx.x;
    if (e < E) atomicAdd(&P[ei[E + e]], 1);
}

__global__ __launch_bounds__(1024) void scan_block(
    int* __restrict__ P, int* __restrict__ bsum, int N)
{
    __shared__ int sdata[1024];
    int i = blockIdx.x * 1024 + threadIdx.x;
    int v = (i < N) ? P[i] : 0;
    sdata[threadIdx.x] = v;
    __syncthreads();
    for (int off = 1; off < 1024; off <<= 1) {
        int t = (threadIdx.x >= off) ? sdata[threadIdx.x - off] : 0;
        __syncthreads();
        sdata[threadIdx.x] += t;
        __syncthreads();
    }
    int incl = sdata[threadIdx.x];
    if (i < N) P[i] = incl - v;              // exclusive
    if (threadIdx.x == 1023) bsum[blockIdx.x] = incl;
}

__global__ __launch_bounds__(64) void scan_bsum(int* __restrict__ bsum, int NB)
{
    if (threadIdx.x == 0) {
        int run = 0;
        for (int b = 0; b < NB; b++) { int t = bsum[b]; bsum[b] = run; run += t; }
    }
}

__global__ __launch_bounds__(1024) void scan_add(
    int* __restrict__ P, const int* __restrict__ bsum, int N)
{
    int i = blockIdx.x * 1024 + threadIdx.x;
    if (i < N) P[i] += bsum[blockIdx.x];
}

__global__ __launch_bounds__(256) void scatter(
    const int* __restrict__ ei, int* __restrict__ P,
    int* __restrict__ sorted_src, int E)
{
    int e = blockIdx.x * 256 + threadIdx.x;
    if (e < E) {
        int dst = ei[E + e];
        int pos = atomicAdd(&P[dst], 1);
        sorted_src[pos] = ei[e];
    }
}

// ---------------------------------------------------------------------------
// Kernel 4: segmented attention reduce + fused normalize. One wave per node.
// After scatter, P[n] == rowptr[n+1]; segment n = [P[n-1], P[n]), P[-1]=0.
// Lane l owns output elements 2l,2l+1; head = l>>3 (8 lanes/head).
// ---------------------------------------------------------------------------
__global__ __launch_bounds__(256) void segment_attn(
    const float* __restrict__ qkv, const int* __restrict__ P,
    const int* __restrict__ sorted_src, float* __restrict__ out, int N)
{
    int wave = (blockIdx.x * 256 + threadIdx.x) >> 6;
    int lane = threadIdx.x & 63;
    if (wave >= N) return;
    int n = wave;
    int start = (n == 0) ? 0 : P[n - 1];
    int end   = P[n];

    float2 q = ((const float2*)(qkv + (size_t)n * QKVD))[lane];
    float accx = 0.f, accy = 0.f, z = 0.f;

    for (int j = start; j < end; j++) {
        int src = sorted_src[j];
        const float* row = qkv + (size_t)src * QKVD;
        float2 k = ((const float2*)(row + OUTD))[lane];
        float2 v = ((const float2*)(row + 2 * OUTD))[lane];
        float p = k.x * q.x + k.y * q.y;
        p += __shfl_xor(p, 1);
        p += __shfl_xor(p, 2);
        p += __shfl_xor(p, 4);           // dot over 16 dims within 8-lane head group
        p *= 0.25f;                      // 1/sqrt(16)
        p = fminf(fmaxf(p, -5.f), 5.f);
        float s = __expf(p);
        accx += v.x * s; accy += v.y * s;
        z += s;
    }
    float inv = 1.f / (z + 1e-6f);
    float2 o; o.x = accx * inv; o.y = accy * inv;
    ((float2*)(out + (size_t)n * OUTD))[lane] = o;
}

extern "C" void kernel_launch(void* const* d_in, const int* in_sizes, int n_in,
                              void* d_out, int out_size, void* d_ws, size_t ws_size,
                              hipStream_t stream) {
    const float* x  = (const float*)d_in[0];
    const int*   ei = (const int*)d_in[1];
    const float* Wq = (const float*)d_in[4];
    const float* bq = (const float*)d_in[5];
    const float* Wk = (const float*)d_in[6];
    const float* bk = (const float*)d_in[7];
    const float* Wv = (const float*)d_in[8];
    const float* bv = (const float*)d_in[9];
    float* out = (float*)d_out;

    const int N = in_sizes[0] / IN_DIM;     // 100000
    const int E = in_sizes[1] / 2;          // 800000

    char* wsb = (char*)d_ws;
    float* qkv       = (float*)wsb;                               // N*384 f32
    int*   P         = (int*)(wsb + (size_t)N * QKVD * 4);        // N ints
    int*   bsum      = P + N;                                     // 128 ints
    int*   sorted    = bsum + 128;                                // E ints

    const int NB = (N + 1023) / 1024;       // 98 scan blocks

    // zero degree counters
    hipMemsetAsync(P, 0, (size_t)N * 4, stream);

    dim3 ggrid(6, (N + 63) / 64);
    qkv_gemm<<<ggrid, 256, 0, stream>>>(x, Wq, bq, Wk, bk, Wv, bv, qkv, N);

    histo<<<(E + 255) / 256, 256, 0, stream>>>(ei, P, E);
    scan_block<<<NB, 1024, 0, stream>>>(P, bsum, N);
    scan_bsum<<<1, 64, 0, stream>>>(bsum, NB);
    scan_add<<<NB, 1024, 0, stream>>>(P, bsum, N);
    scatter<<<(E + 255) / 256, 256, 0, stream>>>(ei, P, sorted, E);

    segment_attn<<<(N * 64 + 255) / 256, 256, 0, stream>>>(qkv, P, sorted, out, N);
}

// Round 3
// 403.066 us; speedup vs baseline: 15.2669x; 1.2571x over previous
//
#include <hip/hip_runtime.h>

#define IN_DIM   128
#define NH       8
#define HD       16
#define OUTD     128   // NH*HD

typedef unsigned short ushort_t;
typedef unsigned int   uint_t;
typedef __bf16 bf16x8 __attribute__((ext_vector_type(8)));
typedef float  f32x4  __attribute__((ext_vector_type(4)));

__device__ __forceinline__ float bf2f(ushort_t u) {
    return __uint_as_float(((uint_t)u) << 16);
}
__device__ __forceinline__ ushort_t f2bf(float f) {
    uint_t u = __float_as_uint(f);
    u += 0x7FFFu + ((u >> 16) & 1u);      // RNE
    return (ushort_t)(u >> 16);
}

// ---------------------------------------------------------------------------
// Kernel 1: fused QKV projection with bf16 MFMA.
// Block: 384 threads (6 waves). Tile: 64 rows x 384 cols (Q|K|V, 128 each).
// Wave w owns cols [w*64, w*64+64): w=0,1 -> Q; 2,3 -> K; 4,5 -> V.
// LDS k-packed layout: As[kgrp][row][8], Bs[kgrp][col][8] so A/B fragment
// reads are single ds_read_b128 (16B/lane, 2-way phase conflict = free).
// Outputs: Qb bf16 [N][128], KVb bf16 [N][256] (K at 0..127, V at 128..255).
// ---------------------------------------------------------------------------
__global__ __launch_bounds__(384) void qkv_gemm(
    const float* __restrict__ x,
    const float* __restrict__ Wq, const float* __restrict__ bq,
    const float* __restrict__ Wk, const float* __restrict__ bk,
    const float* __restrict__ Wv, const float* __restrict__ bv,
    ushort_t* __restrict__ Qb, ushort_t* __restrict__ KVb, int N)
{
    __shared__ ushort_t As[4 * 64 * 8];    // 4 KB
    __shared__ ushort_t Bs[4 * 384 * 8];   // 24 KB

    const int tid  = threadIdx.x;
    const int w    = tid >> 6;        // wave 0..5
    const int quad = (tid >> 4) & 3;
    const int l15  = tid & 15;
    const int row0 = blockIdx.x * 64;

    const int mat = w >> 1;           // 0=Q,1=K,2=V
    const int c   = tid;              // staging column 0..383
    const float* Wp = (c < 128) ? Wq : (c < 256) ? Wk : Wv;
    const int cw_st = c & 127;

    f32x4 acc[4][4];
#pragma unroll
    for (int r = 0; r < 4; r++)
#pragma unroll
        for (int cs = 0; cs < 4; cs++) acc[r][cs] = (f32x4){0.f, 0.f, 0.f, 0.f};

    for (int kt = 0; kt < 4; kt++) {
        const int k0 = kt * 32;
        // ---- stage A: 64 rows x 32 k (threads 0..255) ----
        if (tid < 256) {
            int row  = tid >> 2;
            int kgrp = tid & 3;
            int grow = row0 + row; if (grow > N - 1) grow = N - 1;
            const float* xp = x + (size_t)grow * IN_DIM + k0 + kgrp * 8;
            float4 f0 = *(const float4*)xp;
            float4 f1 = *(const float4*)(xp + 4);
            union { ushort_t h[8]; uint4 u; } t;
            t.h[0] = f2bf(f0.x); t.h[1] = f2bf(f0.y);
            t.h[2] = f2bf(f0.z); t.h[3] = f2bf(f0.w);
            t.h[4] = f2bf(f1.x); t.h[5] = f2bf(f1.y);
            t.h[6] = f2bf(f1.z); t.h[7] = f2bf(f1.w);
            *(uint4*)&As[((kgrp << 6) + row) * 8] = t.u;
        }
        // ---- stage B: 32 k x 384 cols, transposed into k-packed layout ----
        {
#pragma unroll
            for (int g = 0; g < 4; g++) {
                union { ushort_t h[8]; uint4 u; } t;
#pragma unroll
                for (int j = 0; j < 8; j++)
                    t.h[j] = f2bf(Wp[(size_t)(k0 + g * 8 + j) * OUTD + cw_st]);
                *(uint4*)&Bs[((g * 384) + c) * 8] = t.u;
            }
        }
        __syncthreads();

        // ---- compute: 4 row-subtiles x 4 col-subtiles ----
        bf16x8 af[4], bf[4];
#pragma unroll
        for (int r = 0; r < 4; r++)
            af[r] = *(const bf16x8*)&As[((quad << 6) + r * 16 + l15) * 8];
#pragma unroll
        for (int cs = 0; cs < 4; cs++)
            bf[cs] = *(const bf16x8*)&Bs[((quad * 384) + (w << 6) + cs * 16 + l15) * 8];
#pragma unroll
        for (int r = 0; r < 4; r++)
#pragma unroll
            for (int cs = 0; cs < 4; cs++)
                acc[r][cs] = __builtin_amdgcn_mfma_f32_16x16x32_bf16(
                    af[r], bf[cs], acc[r][cs], 0, 0, 0);
        __syncthreads();
    }

    // ---- epilogue: bias add, cvt bf16, store ----
    const float* Bp = (mat == 0) ? bq : (mat == 1) ? bk : bv;
#pragma unroll
    for (int cs = 0; cs < 4; cs++) {
        int cw = ((w & 1) << 6) + cs * 16 + l15;   // 0..127 within matrix
        float bias = Bp[cw];
#pragma unroll
        for (int r = 0; r < 4; r++) {
#pragma unroll
            for (int reg = 0; reg < 4; reg++) {
                int row = row0 + r * 16 + (quad << 2) + reg;
                if (row < N) {
                    ushort_t h = f2bf(acc[r][cs][reg] + bias);
                    if (mat == 0) Qb[(size_t)row * 128 + cw] = h;
                    else KVb[(size_t)row * 256 + ((mat == 1) ? 0 : 128) + cw] = h;
                }
            }
        }
    }
}

// ---------------------------------------------------------------------------
// CSR build: histogram -> block scan -> scatter (counting sort of edges by dst)
// ---------------------------------------------------------------------------
__global__ __launch_bounds__(256) void histo(
    const int* __restrict__ ei, int* __restrict__ P, int E)
{
    int e = blockIdx.x * 256 + threadIdx.x;
    if (e < E) atomicAdd(&P[ei[E + e]], 1);
}

__global__ __launch_bounds__(1024) void scan_block(
    int* __restrict__ P, int* __restrict__ bsum, int N)
{
    __shared__ int sdata[1024];
    int i = blockIdx.x * 1024 + threadIdx.x;
    int v = (i < N) ? P[i] : 0;
    sdata[threadIdx.x] = v;
    __syncthreads();
    for (int off = 1; off < 1024; off <<= 1) {
        int t = (threadIdx.x >= off) ? sdata[threadIdx.x - off] : 0;
        __syncthreads();
        sdata[threadIdx.x] += t;
        __syncthreads();
    }
    int incl = sdata[threadIdx.x];
    if (i < N) P[i] = incl - v;              // exclusive
    if (threadIdx.x == 1023) bsum[blockIdx.x] = incl;
}

__global__ __launch_bounds__(128) void scan_bsum(int* __restrict__ bsum, int NB)
{
    __shared__ int sdata[128];
    int t = threadIdx.x;
    int v = (t < NB) ? bsum[t] : 0;
    sdata[t] = v;
    __syncthreads();
    for (int off = 1; off < 128; off <<= 1) {
        int a = (t >= off) ? sdata[t - off] : 0;
        __syncthreads();
        sdata[t] += a;
        __syncthreads();
    }
    if (t < NB) bsum[t] = sdata[t] - v;      // exclusive
}

__global__ __launch_bounds__(1024) void scan_add(
    int* __restrict__ P, const int* __restrict__ bsum, int N)
{
    int i = blockIdx.x * 1024 + threadIdx.x;
    if (i < N) P[i] += bsum[blockIdx.x];
}

__global__ __launch_bounds__(256) void scatter(
    const int* __restrict__ ei, int* __restrict__ P,
    int* __restrict__ sorted_src, int E)
{
    int e = blockIdx.x * 256 + threadIdx.x;
    if (e < E) {
        int dst = ei[E + e];
        int pos = atomicAdd(&P[dst], 1);
        sorted_src[pos] = ei[e];
    }
}

// ---------------------------------------------------------------------------
// Segmented attention reduce + fused normalize. One wave per node.
// After scatter, P[n] == rowptr[n+1]; segment n = [P[n-1], P[n]), P[-1]=0.
// Lane l owns output elements 2l,2l+1; head = l>>3 (8 lanes/head).
// Q/K/V read as bf16 (exact bit-shift expand), accumulate fp32.
// ---------------------------------------------------------------------------
__global__ __launch_bounds__(256) void segment_attn(
    const ushort_t* __restrict__ Qb, const ushort_t* __restrict__ KVb,
    const int* __restrict__ P, const int* __restrict__ sorted_src,
    float* __restrict__ out, int N)
{
    int wave = (blockIdx.x * 256 + threadIdx.x) >> 6;
    int lane = threadIdx.x & 63;
    if (wave >= N) return;
    int n = wave;
    int start = (n == 0) ? 0 : P[n - 1];
    int end   = P[n];

    uint_t qu = ((const uint_t*)(Qb + (size_t)n * 128))[lane];
    float qx = bf2f((ushort_t)(qu & 0xFFFF));
    float qy = bf2f((ushort_t)(qu >> 16));

    float accx = 0.f, accy = 0.f, z = 0.f;

    for (int j = start; j < end; j++) {
        int src = sorted_src[j];
        const uint_t* kv = (const uint_t*)(KVb + (size_t)src * 256);
        uint_t ku = kv[lane];
        uint_t vu = kv[64 + lane];
        float kx = bf2f((ushort_t)(ku & 0xFFFF));
        float ky = bf2f((ushort_t)(ku >> 16));
        float p = kx * qx + ky * qy;
        p += __shfl_xor(p, 1);
        p += __shfl_xor(p, 2);
        p += __shfl_xor(p, 4);           // dot over 16 dims within 8-lane head
        p *= 0.25f;                      // 1/sqrt(16)
        p = fminf(fmaxf(p, -5.f), 5.f);
        float s = __expf(p);
        accx += bf2f((ushort_t)(vu & 0xFFFF)) * s;
        accy += bf2f((ushort_t)(vu >> 16)) * s;
        z += s;
    }
    float inv = 1.f / (z + 1e-6f);
    float2 o; o.x = accx * inv; o.y = accy * inv;
    ((float2*)(out + (size_t)n * OUTD))[lane] = o;
}

extern "C" void kernel_launch(void* const* d_in, const int* in_sizes, int n_in,
                              void* d_out, int out_size, void* d_ws, size_t ws_size,
                              hipStream_t stream) {
    const float* x  = (const float*)d_in[0];
    const int*   ei = (const int*)d_in[1];
    const float* Wq = (const float*)d_in[4];
    const float* bq = (const float*)d_in[5];
    const float* Wk = (const float*)d_in[6];
    const float* bk = (const float*)d_in[7];
    const float* Wv = (const float*)d_in[8];
    const float* bv = (const float*)d_in[9];
    float* out = (float*)d_out;

    const int N = in_sizes[0] / IN_DIM;     // 100000
    const int E = in_sizes[1] / 2;          // 800000

    char* wsb = (char*)d_ws;
    ushort_t* Qb  = (ushort_t*)wsb;                     // N*128 bf16
    ushort_t* KVb = Qb + (size_t)N * 128;               // N*256 bf16
    int* P      = (int*)(KVb + (size_t)N * 256);        // N ints
    int* bsum   = P + N;                                // 128 ints
    int* sorted = bsum + 128;                           // E ints

    const int NB = (N + 1023) / 1024;       // 98 scan blocks

    hipMemsetAsync(P, 0, (size_t)N * 4, stream);

    qkv_gemm<<<(N + 63) / 64, 384, 0, stream>>>(x, Wq, bq, Wk, bk, Wv, bv,
                                                Qb, KVb, N);

    histo<<<(E + 255) / 256, 256, 0, stream>>>(ei, P, E);
    scan_block<<<NB, 1024, 0, stream>>>(P, bsum, N);
    scan_bsum<<<1, 128, 0, stream>>>(bsum, NB);
    scan_add<<<NB, 1024, 0, stream>>>(P, bsum, N);
    scatter<<<(E + 255) / 256, 256, 0, stream>>>(ei, P, sorted, E);

    segment_attn<<<(N * 64 + 255) / 256, 256, 0, stream>>>(Qb, KVb, P, sorted,
                                                           out, N);
}

// Round 4
// 347.500 us; speedup vs baseline: 17.7081x; 1.1599x over previous
//
#include <hip/hip_runtime.h>

#define IN_DIM   128
#define NH       8
#define HD       16
#define OUTD     128   // NH*HD

typedef unsigned short ushort_t;
typedef unsigned int   uint_t;
typedef __bf16 bf16x8 __attribute__((ext_vector_type(8)));
typedef float  f32x4  __attribute__((ext_vector_type(4)));

__device__ __forceinline__ float bf2f(ushort_t u) {
    return __uint_as_float(((uint_t)u) << 16);
}
__device__ __forceinline__ ushort_t f2bf(float f) {
    uint_t u = __float_as_uint(f);
    u += 0x7FFFu + ((u >> 16) & 1u);      // RNE
    return (ushort_t)(u >> 16);
}

// ---------------------------------------------------------------------------
// prep_w: W[k][c] fp32 (3 mats) -> Wt[col][k] bf16, col in [0,384)
// (col<128 -> Wq, <256 -> Wk, else Wv). 48 blocks, 32x32 tile transpose.
// ---------------------------------------------------------------------------
__global__ __launch_bounds__(256) void prep_w(
    const float* __restrict__ Wq, const float* __restrict__ Wk,
    const float* __restrict__ Wv, ushort_t* __restrict__ Wt)
{
    __shared__ float ld[32][33];
    int mat  = blockIdx.x >> 4;
    int tile = blockIdx.x & 15;
    int k0 = (tile >> 2) * 32, c0 = (tile & 3) * 32;
    const float* W = (mat == 0) ? Wq : (mat == 1) ? Wk : Wv;
    int t = threadIdx.x;
    {
        int k = t >> 3, c4 = (t & 7) * 4;
        float4 f = *(const float4*)&W[(size_t)(k0 + k) * 128 + c0 + c4];
        ld[k][c4 + 0] = f.x; ld[k][c4 + 1] = f.y;
        ld[k][c4 + 2] = f.z; ld[k][c4 + 3] = f.w;
    }
    __syncthreads();
    {
        int c = t >> 3, kg = (t & 7) * 4;
        union { ushort_t h[4]; uint2 u; } o;
        o.h[0] = f2bf(ld[kg + 0][c]); o.h[1] = f2bf(ld[kg + 1][c]);
        o.h[2] = f2bf(ld[kg + 2][c]); o.h[3] = f2bf(ld[kg + 3][c]);
        *(uint2*)&Wt[((size_t)(mat * 128 + c0 + c)) * 128 + k0 + kg] = o.u;
    }
}

// ---------------------------------------------------------------------------
// gemm_histo: blocks [0, ngemm) do the QKV MFMA GEMM (64 rows x 384 cols,
// 6 waves, one col-block of 64 per wave). Blocks >= ngemm do the degree
// histogram (independent work, shares the launch).
// A: LDS k-packed entries [kc(16)][row(64, pad to 65)][8 bf16] — staging
// writes and b128 fragment reads are both <=2-way bank aliased (free).
// B: fragments read directly from global Wt (16B/lane, L2-resident).
// ---------------------------------------------------------------------------
__global__ __launch_bounds__(384) void gemm_histo(
    const float* __restrict__ x, const ushort_t* __restrict__ Wt,
    const float* __restrict__ bq, const float* __restrict__ bk,
    const float* __restrict__ bv,
    const int* __restrict__ ei, int* __restrict__ P,
    ushort_t* __restrict__ Qb, ushort_t* __restrict__ KVb,
    int N, int E, int ngemm, int nhisto)
{
    if ((int)blockIdx.x >= ngemm) {
        int base = ((int)blockIdx.x - ngemm) * 384 + threadIdx.x;
        int stride = nhisto * 384;
        for (int e = base; e < E; e += stride)
            atomicAdd(&P[ei[E + e]], 1);
        return;
    }

    __shared__ ushort_t As[16 * 65 * 8];   // 16.6 KB

    const int tid  = threadIdx.x;
    const int row0 = blockIdx.x * 64;

    // ---- stage A: full 64x128 tile, bf16, one barrier ----
    for (int ch = tid; ch < 1024; ch += 384) {
        int row = ch >> 4;
        int kc  = ch & 15;
        int grow = row0 + row; if (grow > N - 1) grow = N - 1;
        const float* xp = x + (size_t)grow * IN_DIM + kc * 8;
        float4 f0 = *(const float4*)xp;
        float4 f1 = *(const float4*)(xp + 4);
        union { ushort_t h[8]; uint4 u; } tt;
        tt.h[0] = f2bf(f0.x); tt.h[1] = f2bf(f0.y);
        tt.h[2] = f2bf(f0.z); tt.h[3] = f2bf(f0.w);
        tt.h[4] = f2bf(f1.x); tt.h[5] = f2bf(f1.y);
        tt.h[6] = f2bf(f1.z); tt.h[7] = f2bf(f1.w);
        *(uint4*)&As[(kc * 65 + row) * 8] = tt.u;
    }
    __syncthreads();

    const int w    = tid >> 6;        // wave 0..5
    const int quad = (tid >> 4) & 3;
    const int l15  = tid & 15;
    const int colg = w << 6;          // global col base 0..320

    f32x4 acc[4][4];
#pragma unroll
    for (int r = 0; r < 4; r++)
#pragma unroll
        for (int cs = 0; cs < 4; cs++) acc[r][cs] = (f32x4){0.f, 0.f, 0.f, 0.f};

    for (int kt = 0; kt < 4; kt++) {
        bf16x8 bfr[4], af[4];
#pragma unroll
        for (int cs = 0; cs < 4; cs++) {
            int col = colg + cs * 16 + l15;
            bfr[cs] = *(const bf16x8*)&Wt[(size_t)col * 128 + kt * 32 + quad * 8];
        }
        int kc = kt * 4 + quad;
#pragma unroll
        for (int r = 0; r < 4; r++)
            af[r] = *(const bf16x8*)&As[(kc * 65 + r * 16 + l15) * 8];
#pragma unroll
        for (int r = 0; r < 4; r++)
#pragma unroll
            for (int cs = 0; cs < 4; cs++)
                acc[r][cs] = __builtin_amdgcn_mfma_f32_16x16x32_bf16(
                    af[r], bfr[cs], acc[r][cs], 0, 0, 0);
    }

    // ---- epilogue: bias, cvt bf16, store ----
    const int mat = w >> 1;           // 0=Q,1=K,2=V
    const float* Bp = (mat == 0) ? bq : (mat == 1) ? bk : bv;
#pragma unroll
    for (int cs = 0; cs < 4; cs++) {
        int cw = ((w & 1) << 6) + cs * 16 + l15;   // 0..127 within matrix
        float bias = Bp[cw];
#pragma unroll
        for (int r = 0; r < 4; r++) {
#pragma unroll
            for (int reg = 0; reg < 4; reg++) {
                int row = row0 + r * 16 + (quad << 2) + reg;
                if (row < N) {
                    ushort_t h = f2bf(acc[r][cs][reg] + bias);
                    if (mat == 0) Qb[(size_t)row * 128 + cw] = h;
                    else KVb[(size_t)row * 256 + ((mat == 1) ? 0 : 128) + cw] = h;
                }
            }
        }
    }
}

// ---------------------------------------------------------------------------
// Single-pass exclusive scan over P[N] (decoupled lookback).
// desc[b]: bits 32..33 state (0 invalid / 1 aggregate / 2 prefix), low 32 value.
// ---------------------------------------------------------------------------
__global__ __launch_bounds__(1024) void scan_onepass(
    int* __restrict__ P, unsigned long long* __restrict__ desc, int N)
{
    __shared__ int sdata[1024];
    __shared__ int s_prefix;
    int b = blockIdx.x;
    int i = b * 1024 + threadIdx.x;
    int v = (i < N) ? P[i] : 0;
    sdata[threadIdx.x] = v;
    __syncthreads();
    for (int off = 1; off < 1024; off <<= 1) {
        int t = (threadIdx.x >= off) ? sdata[threadIdx.x - off] : 0;
        __syncthreads();
        sdata[threadIdx.x] += t;
        __syncthreads();
    }
    int incl  = sdata[threadIdx.x];
    int total = sdata[1023];

    if (threadIdx.x == 0) {
        unsigned long long st1 = ((unsigned long long)((b == 0) ? 2 : 1) << 32)
                                 | (uint_t)total;
        __hip_atomic_store(&desc[b], st1, __ATOMIC_RELEASE, __HIP_MEMORY_SCOPE_AGENT);
        int prefix = 0;
        if (b > 0) {
            int bb = b - 1;
            for (;;) {
                unsigned long long d = __hip_atomic_load(
                    &desc[bb], __ATOMIC_ACQUIRE, __HIP_MEMORY_SCOPE_AGENT);
                uint_t st = (uint_t)(d >> 32);
                if (st == 0) continue;
                prefix += (int)(uint_t)(d & 0xFFFFFFFFu);
                if (st == 2) break;
                bb--;
            }
            __hip_atomic_store(&desc[b],
                ((unsigned long long)2 << 32) | (uint_t)(prefix + total),
                __ATOMIC_RELEASE, __HIP_MEMORY_SCOPE_AGENT);
        }
        s_prefix = prefix;
    }
    __syncthreads();
    if (i < N) P[i] = s_prefix + incl - v;   // exclusive
}

__global__ __launch_bounds__(256) void scatter(
    const int* __restrict__ ei, int* __restrict__ P,
    int* __restrict__ sorted_src, int E)
{
    int e = blockIdx.x * 256 + threadIdx.x;
    if (e < E) {
        int dst = ei[E + e];
        int pos = atomicAdd(&P[dst], 1);
        sorted_src[pos] = ei[e];
    }
}

// ---------------------------------------------------------------------------
// Segmented attention reduce + fused normalize. One wave per node.
// P[n] == rowptr[n+1] after scatter; segment n = [P[n-1], P[n]), P[-1]=0.
// Src indices prefetched lane-parallel (one coalesced load), broadcast via
// shfl; edge loop unrolled x4 so 8 KV loads are in flight.
// ---------------------------------------------------------------------------
__global__ __launch_bounds__(256) void segment_attn(
    const ushort_t* __restrict__ Qb, const ushort_t* __restrict__ KVb,
    const int* __restrict__ P, const int* __restrict__ sorted_src,
    float* __restrict__ out, int N)
{
    int wave = (blockIdx.x * 256 + threadIdx.x) >> 6;
    int lane = threadIdx.x & 63;
    if (wave >= N) return;
    int n = wave;
    int start = (n == 0) ? 0 : P[n - 1];
    int end   = P[n];
    int deg   = end - start;

    uint_t qu = ((const uint_t*)(Qb + (size_t)n * 128))[lane];
    float qx = bf2f((ushort_t)(qu & 0xFFFF));
    float qy = bf2f((ushort_t)(qu >> 16));

    float accx = 0.f, accy = 0.f, z = 0.f;

    int myidx = (lane < deg) ? sorted_src[start + lane] : 0;

#define PROC(ku, vu)                                                   \
    {                                                                  \
        float kx = bf2f((ushort_t)((ku) & 0xFFFF));                    \
        float ky = bf2f((ushort_t)((ku) >> 16));                       \
        float p = kx * qx + ky * qy;                                   \
        p += __shfl_xor(p, 1);                                         \
        p += __shfl_xor(p, 2);                                         \
        p += __shfl_xor(p, 4);                                         \
        p = fminf(fmaxf(p * 0.25f, -5.f), 5.f);                        \
        float s = __expf(p);                                           \
        accx += bf2f((ushort_t)((vu) & 0xFFFF)) * s;                   \
        accy += bf2f((ushort_t)((vu) >> 16)) * s;                      \
        z += s;                                                        \
    }

    int cnt = (deg < 64) ? deg : 64;
    int t = 0;
    for (; t + 4 <= cnt; t += 4) {
        int s0 = __shfl(myidx, t + 0);
        int s1 = __shfl(myidx, t + 1);
        int s2 = __shfl(myidx, t + 2);
        int s3 = __shfl(myidx, t + 3);
        const uint_t* kv0 = (const uint_t*)(KVb + (size_t)s0 * 256);
        const uint_t* kv1 = (const uint_t*)(KVb + (size_t)s1 * 256);
        const uint_t* kv2 = (const uint_t*)(KVb + (size_t)s2 * 256);
        const uint_t* kv3 = (const uint_t*)(KVb + (size_t)s3 * 256);
        uint_t ku0 = kv0[lane],      ku1 = kv1[lane];
        uint_t ku2 = kv2[lane],      ku3 = kv3[lane];
        uint_t vu0 = kv0[64 + lane], vu1 = kv1[64 + lane];
        uint_t vu2 = kv2[64 + lane], vu3 = kv3[64 + lane];
        PROC(ku0, vu0); PROC(ku1, vu1); PROC(ku2, vu2); PROC(ku3, vu3);
    }
    for (; t < cnt; t++) {
        int s0 = __shfl(myidx, t);
        const uint_t* kv0 = (const uint_t*)(KVb + (size_t)s0 * 256);
        uint_t ku0 = kv0[lane], vu0 = kv0[64 + lane];
        PROC(ku0, vu0);
    }
    // overflow fallback (deg > 64): statistically never taken, kept for safety
    for (int j = start + 64; j < end; j++) {
        int s0 = sorted_src[j];
        const uint_t* kv0 = (const uint_t*)(KVb + (size_t)s0 * 256);
        uint_t ku0 = kv0[lane], vu0 = kv0[64 + lane];
        PROC(ku0, vu0);
    }
#undef PROC

    float inv = 1.f / (z + 1e-6f);
    float2 o; o.x = accx * inv; o.y = accy * inv;
    ((float2*)(out + (size_t)n * OUTD))[lane] = o;
}

extern "C" void kernel_launch(void* const* d_in, const int* in_sizes, int n_in,
                              void* d_out, int out_size, void* d_ws, size_t ws_size,
                              hipStream_t stream) {
    const float* x  = (const float*)d_in[0];
    const int*   ei = (const int*)d_in[1];
    const float* Wq = (const float*)d_in[4];
    const float* bq = (const float*)d_in[5];
    const float* Wk = (const float*)d_in[6];
    const float* bk = (const float*)d_in[7];
    const float* Wv = (const float*)d_in[8];
    const float* bv = (const float*)d_in[9];
    float* out = (float*)d_out;

    const int N = in_sizes[0] / IN_DIM;     // 100000
    const int E = in_sizes[1] / 2;          // 800000

    char* wsb = (char*)d_ws;
    ushort_t* Qb  = (ushort_t*)wsb;                          // N*128 bf16
    ushort_t* KVb = Qb + (size_t)N * 128;                    // N*256 bf16
    ushort_t* Wt  = KVb + (size_t)N * 256;                   // 384*128 bf16
    int* P = (int*)(Wt + 384 * 128);                         // N ints
    unsigned long long* desc = (unsigned long long*)((char*)P + (size_t)N * 4);
    int* sorted = (int*)((char*)desc + 1024);                // E ints

    const int ngemm  = (N + 63) / 64;       // 1563
    const int nhisto = 512;
    const int NB     = (N + 1023) / 1024;   // 98 scan blocks

    // zero degree counters + scan descriptors in one memset
    hipMemsetAsync(P, 0, (size_t)N * 4 + 1024, stream);

    prep_w<<<48, 256, 0, stream>>>(Wq, Wk, Wv, Wt);
    gemm_histo<<<ngemm + nhisto, 384, 0, stream>>>(
        x, Wt, bq, bk, bv, ei, P, Qb, KVb, N, E, ngemm, nhisto);
    scan_onepass<<<NB, 1024, 0, stream>>>(P, desc, N);
    scatter<<<(E + 255) / 256, 256, 0, stream>>>(ei, P, sorted, E);
    segment_attn<<<(N * 64 + 255) / 256, 256, 0, stream>>>(Qb, KVb, P, sorted,
                                                           out, N);
}

// Round 5
// 314.210 us; speedup vs baseline: 19.5842x; 1.1060x over previous
//
#include <hip/hip_runtime.h>

#define IN_DIM   128
#define NH       8
#define HD       16
#define OUTD     128   // NH*HD
#define QKVD     384   // Q|K|V interleaved per node, bf16

typedef unsigned short ushort_t;
typedef unsigned int   uint_t;
typedef __bf16 bf16x8 __attribute__((ext_vector_type(8)));
typedef float  f32x4  __attribute__((ext_vector_type(4)));

__device__ __forceinline__ float bf2f(ushort_t u) {
    return __uint_as_float(((uint_t)u) << 16);
}
__device__ __forceinline__ ushort_t f2bf(float f) {
    uint_t u = __float_as_uint(f);
    u += 0x7FFFu + ((u >> 16) & 1u);      // RNE
    return (ushort_t)(u >> 16);
}

// ---------------------------------------------------------------------------
// prep_w: W[k][c] fp32 (3 mats) -> Wt[col][k] bf16, col in [0,384)
// ---------------------------------------------------------------------------
__global__ __launch_bounds__(256) void prep_w(
    const float* __restrict__ Wq, const float* __restrict__ Wk,
    const float* __restrict__ Wv, ushort_t* __restrict__ Wt)
{
    __shared__ float ld[32][33];
    int mat  = blockIdx.x >> 4;
    int tile = blockIdx.x & 15;
    int k0 = (tile >> 2) * 32, c0 = (tile & 3) * 32;
    const float* W = (mat == 0) ? Wq : (mat == 1) ? Wk : Wv;
    int t = threadIdx.x;
    {
        int k = t >> 3, c4 = (t & 7) * 4;
        float4 f = *(const float4*)&W[(size_t)(k0 + k) * 128 + c0 + c4];
        ld[k][c4 + 0] = f.x; ld[k][c4 + 1] = f.y;
        ld[k][c4 + 2] = f.z; ld[k][c4 + 3] = f.w;
    }
    __syncthreads();
    {
        int c = t >> 3, kg = (t & 7) * 4;
        union { ushort_t h[4]; uint2 u; } o;
        o.h[0] = f2bf(ld[kg + 0][c]); o.h[1] = f2bf(ld[kg + 1][c]);
        o.h[2] = f2bf(ld[kg + 2][c]); o.h[3] = f2bf(ld[kg + 3][c]);
        *(uint2*)&Wt[((size_t)(mat * 128 + c0 + c)) * 128 + k0 + kg] = o.u;
    }
}

// ---------------------------------------------------------------------------
// gemm_histo: blocks [0, ngemm) do the QKV MFMA GEMM (64 rows x 384 cols,
// 6 waves, one 64-col block per wave). Blocks >= ngemm do the degree
// histogram. A staged in LDS k-packed; B fragments direct from global Wt.
// Epilogue: acc -> LDS transpose (2 halves of 32 rows) -> coalesced
// dwordx4 stores into contiguous qkv[N][384] bf16.
// ---------------------------------------------------------------------------
__global__ __launch_bounds__(384) void gemm_histo(
    const float* __restrict__ x, const ushort_t* __restrict__ Wt,
    const float* __restrict__ bq, const float* __restrict__ bk,
    const float* __restrict__ bv,
    const int* __restrict__ ei, int* __restrict__ P,
    ushort_t* __restrict__ qkv,
    int N, int E, int ngemm, int nhisto)
{
    if ((int)blockIdx.x >= ngemm) {
        int base = ((int)blockIdx.x - ngemm) * 384 + threadIdx.x;
        int stride = nhisto * 384;
        for (int e = base; e < E; e += stride)
            atomicAdd(&P[ei[E + e]], 1);
        return;
    }

    // union buffer: staging needs 16*65*8 = 33280 ushorts? no: 16*65*8 = 8320
    // entries of 8 ushorts... As index = (kc*65+row)*8, max = (15*65+63)*8+8
    // = 8312+... = 8320*... Just size it explicitly:
    __shared__ ushort_t sh[16640];   // 33.3 KB; staging uses 16*65*64=16640? see below

    const int tid  = threadIdx.x;
    const int row0 = blockIdx.x * 64;

    // ---- stage A: 64 rows x 128 k, bf16, k-packed [kc(16)][row(65 pad)][8] ----
    for (int ch = tid; ch < 1024; ch += 384) {
        int row = ch >> 4;
        int kc  = ch & 15;
        int grow = row0 + row; if (grow > N - 1) grow = N - 1;
        const float* xp = x + (size_t)grow * IN_DIM + kc * 8;
        float4 f0 = *(const float4*)xp;
        float4 f1 = *(const float4*)(xp + 4);
        union { ushort_t h[8]; uint4 u; } tt;
        tt.h[0] = f2bf(f0.x); tt.h[1] = f2bf(f0.y);
        tt.h[2] = f2bf(f0.z); tt.h[3] = f2bf(f0.w);
        tt.h[4] = f2bf(f1.x); tt.h[5] = f2bf(f1.y);
        tt.h[6] = f2bf(f1.z); tt.h[7] = f2bf(f1.w);
        *(uint4*)&sh[(kc * 65 + row) * 8] = tt.u;
    }
    __syncthreads();

    const int w    = tid >> 6;        // wave 0..5
    const int quad = (tid >> 4) & 3;
    const int l15  = tid & 15;
    const int colg = w << 6;          // global col base 0..320

    f32x4 acc[4][4];
#pragma unroll
    for (int r = 0; r < 4; r++)
#pragma unroll
        for (int cs = 0; cs < 4; cs++) acc[r][cs] = (f32x4){0.f, 0.f, 0.f, 0.f};

    for (int kt = 0; kt < 4; kt++) {
        bf16x8 bfr[4], af[4];
#pragma unroll
        for (int cs = 0; cs < 4; cs++) {
            int col = colg + cs * 16 + l15;
            bfr[cs] = *(const bf16x8*)&Wt[(size_t)col * 128 + kt * 32 + quad * 8];
        }
        int kc = kt * 4 + quad;
#pragma unroll
        for (int r = 0; r < 4; r++)
            af[r] = *(const bf16x8*)&sh[(kc * 65 + r * 16 + l15) * 8];
#pragma unroll
        for (int r = 0; r < 4; r++)
#pragma unroll
            for (int cs = 0; cs < 4; cs++)
                acc[r][cs] = __builtin_amdgcn_mfma_f32_16x16x32_bf16(
                    af[r], bfr[cs], acc[r][cs], 0, 0, 0);
    }

    // ---- epilogue: bias + cvt, LDS transpose in 2 halves, coalesced store ----
    const int mat = w >> 1;           // 0=Q,1=K,2=V
    const float* Bp = (mat == 0) ? bq : (mat == 1) ? bk : bv;
    float bias[4];
#pragma unroll
    for (int cs = 0; cs < 4; cs++)
        bias[cs] = Bp[((w & 1) << 6) + cs * 16 + l15];

#define EPS 392   // padded row stride (bf16 units): quads land 2-way on banks
#pragma unroll
    for (int h = 0; h < 2; h++) {
        __syncthreads();   // LDS free (staging reads / previous half done)
#pragma unroll
        for (int r = 2 * h; r < 2 * h + 2; r++) {
            int lrow = r * 16 + (quad << 2) - h * 32;
#pragma unroll
            for (int cs = 0; cs < 4; cs++) {
                int col = (w << 6) + cs * 16 + l15;
#pragma unroll
                for (int reg = 0; reg < 4; reg++)
                    sh[(lrow + reg) * EPS + col] = f2bf(acc[r][cs][reg] + bias[cs]);
            }
        }
        __syncthreads();
        // read out: 32 rows x 384 cols = 1536 chunks of 8 bf16; 4 per thread
#pragma unroll
        for (int i = 0; i < 4; i++) {
            int c = tid + i * 384;
            int row = c / 48;
            int col = (c % 48) * 8;
            int grow = row0 + h * 32 + row;
            if (grow < N) {
                uint4 val = *(const uint4*)&sh[row * EPS + col];
                *(uint4*)&qkv[(size_t)grow * QKVD + col] = val;
            }
        }
    }
#undef EPS
}

// ---------------------------------------------------------------------------
// Single-pass exclusive scan over P[N] (decoupled lookback).
// ---------------------------------------------------------------------------
__global__ __launch_bounds__(1024) void scan_onepass(
    int* __restrict__ P, unsigned long long* __restrict__ desc, int N)
{
    __shared__ int sdata[1024];
    __shared__ int s_prefix;
    int b = blockIdx.x;
    int i = b * 1024 + threadIdx.x;
    int v = (i < N) ? P[i] : 0;
    sdata[threadIdx.x] = v;
    __syncthreads();
    for (int off = 1; off < 1024; off <<= 1) {
        int t = (threadIdx.x >= off) ? sdata[threadIdx.x - off] : 0;
        __syncthreads();
        sdata[threadIdx.x] += t;
        __syncthreads();
    }
    int incl  = sdata[threadIdx.x];
    int total = sdata[1023];

    if (threadIdx.x == 0) {
        unsigned long long st1 = ((unsigned long long)((b == 0) ? 2 : 1) << 32)
                                 | (uint_t)total;
        __hip_atomic_store(&desc[b], st1, __ATOMIC_RELEASE, __HIP_MEMORY_SCOPE_AGENT);
        int prefix = 0;
        if (b > 0) {
            int bb = b - 1;
            for (;;) {
                unsigned long long d = __hip_atomic_load(
                    &desc[bb], __ATOMIC_ACQUIRE, __HIP_MEMORY_SCOPE_AGENT);
                uint_t st = (uint_t)(d >> 32);
                if (st == 0) continue;
                prefix += (int)(uint_t)(d & 0xFFFFFFFFu);
                if (st == 2) break;
                bb--;
            }
            __hip_atomic_store(&desc[b],
                ((unsigned long long)2 << 32) | (uint_t)(prefix + total),
                __ATOMIC_RELEASE, __HIP_MEMORY_SCOPE_AGENT);
        }
        s_prefix = prefix;
    }
    __syncthreads();
    if (i < N) P[i] = s_prefix + incl - v;   // exclusive
}

__global__ __launch_bounds__(256) void scatter(
    const int* __restrict__ ei, int* __restrict__ P,
    int* __restrict__ sorted_src, int E)
{
    int e = blockIdx.x * 256 + threadIdx.x;
    if (e < E) {
        int dst = ei[E + e];
        int pos = atomicAdd(&P[dst], 1);
        sorted_src[pos] = ei[e];
    }
}

// ---------------------------------------------------------------------------
// Segmented attention reduce + fused normalize. One wave per node.
// P[n] == rowptr[n+1] after scatter; segment n = [P[n-1], P[n]), P[-1]=0.
// qkv row: Q cols 0..127, K 128..255, V 256..383 (bf16).
// ---------------------------------------------------------------------------
__global__ __launch_bounds__(256) void segment_attn(
    const ushort_t* __restrict__ qkv,
    const int* __restrict__ P, const int* __restrict__ sorted_src,
    float* __restrict__ out, int N)
{
    int wave = (blockIdx.x * 256 + threadIdx.x) >> 6;
    int lane = threadIdx.x & 63;
    if (wave >= N) return;
    int n = wave;
    int start = (n == 0) ? 0 : P[n - 1];
    int end   = P[n];
    int deg   = end - start;

    uint_t qu = ((const uint_t*)(qkv + (size_t)n * QKVD))[lane];
    float qx = bf2f((ushort_t)(qu & 0xFFFF));
    float qy = bf2f((ushort_t)(qu >> 16));

    float accx = 0.f, accy = 0.f, z = 0.f;

    int myidx = (lane < deg) ? sorted_src[start + lane] : 0;

#define PROC(ku, vu)                                                   \
    {                                                                  \
        float kx = bf2f((ushort_t)((ku) & 0xFFFF));                    \
        float ky = bf2f((ushort_t)((ku) >> 16));                       \
        float p = kx * qx + ky * qy;                                   \
        p += __shfl_xor(p, 1);                                         \
        p += __shfl_xor(p, 2);                                         \
        p += __shfl_xor(p, 4);                                         \
        p = fminf(fmaxf(p * 0.25f, -5.f), 5.f);                        \
        float s = __expf(p);                                           \
        accx += bf2f((ushort_t)((vu) & 0xFFFF)) * s;                   \
        accy += bf2f((ushort_t)((vu) >> 16)) * s;                      \
        z += s;                                                        \
    }

    int cnt = (deg < 64) ? deg : 64;
    int t = 0;
    for (; t + 4 <= cnt; t += 4) {
        int s0 = __shfl(myidx, t + 0);
        int s1 = __shfl(myidx, t + 1);
        int s2 = __shfl(myidx, t + 2);
        int s3 = __shfl(myidx, t + 3);
        const uint_t* kv0 = (const uint_t*)(qkv + (size_t)s0 * QKVD + 128);
        const uint_t* kv1 = (const uint_t*)(qkv + (size_t)s1 * QKVD + 128);
        const uint_t* kv2 = (const uint_t*)(qkv + (size_t)s2 * QKVD + 128);
        const uint_t* kv3 = (const uint_t*)(qkv + (size_t)s3 * QKVD + 128);
        uint_t ku0 = kv0[lane],      ku1 = kv1[lane];
        uint_t ku2 = kv2[lane],      ku3 = kv3[lane];
        uint_t vu0 = kv0[64 + lane], vu1 = kv1[64 + lane];
        uint_t vu2 = kv2[64 + lane], vu3 = kv3[64 + lane];
        PROC(ku0, vu0); PROC(ku1, vu1); PROC(ku2, vu2); PROC(ku3, vu3);
    }
    for (; t < cnt; t++) {
        int s0 = __shfl(myidx, t);
        const uint_t* kv0 = (const uint_t*)(qkv + (size_t)s0 * QKVD + 128);
        uint_t ku0 = kv0[lane], vu0 = kv0[64 + lane];
        PROC(ku0, vu0);
    }
    for (int j = start + 64; j < end; j++) {   // deg>64 fallback
        int s0 = sorted_src[j];
        const uint_t* kv0 = (const uint_t*)(qkv + (size_t)s0 * QKVD + 128);
        uint_t ku0 = kv0[lane], vu0 = kv0[64 + lane];
        PROC(ku0, vu0);
    }
#undef PROC

    float inv = 1.f / (z + 1e-6f);
    float2 o; o.x = accx * inv; o.y = accy * inv;
    ((float2*)(out + (size_t)n * OUTD))[lane] = o;
}

extern "C" void kernel_launch(void* const* d_in, const int* in_sizes, int n_in,
                              void* d_out, int out_size, void* d_ws, size_t ws_size,
                              hipStream_t stream) {
    const float* x  = (const float*)d_in[0];
    const int*   ei = (const int*)d_in[1];
    const float* Wq = (const float*)d_in[4];
    const float* bq = (const float*)d_in[5];
    const float* Wk = (const float*)d_in[6];
    const float* bk = (const float*)d_in[7];
    const float* Wv = (const float*)d_in[8];
    const float* bv = (const float*)d_in[9];
    float* out = (float*)d_out;

    const int N = in_sizes[0] / IN_DIM;     // 100000
    const int E = in_sizes[1] / 2;          // 800000

    char* wsb = (char*)d_ws;
    ushort_t* qkv = (ushort_t*)wsb;                          // N*384 bf16
    ushort_t* Wt  = qkv + (size_t)N * QKVD;                  // 384*128 bf16
    int* P = (int*)(Wt + 384 * 128);                         // N ints
    unsigned long long* desc = (unsigned long long*)((char*)P + (size_t)N * 4);
    int* sorted = (int*)((char*)desc + 1024);                // E ints

    const int ngemm  = (N + 63) / 64;       // 1563
    const int nhisto = 512;
    const int NB     = (N + 1023) / 1024;   // 98 scan blocks

    hipMemsetAsync(P, 0, (size_t)N * 4 + 1024, stream);

    prep_w<<<48, 256, 0, stream>>>(Wq, Wk, Wv, Wt);
    gemm_histo<<<ngemm + nhisto, 384, 0, stream>>>(
        x, Wt, bq, bk, bv, ei, P, qkv, N, E, ngemm, nhisto);
    scan_onepass<<<NB, 1024, 0, stream>>>(P, desc, N);
    scatter<<<(E + 255) / 256, 256, 0, stream>>>(ei, P, sorted, E);
    segment_attn<<<(N * 64 + 255) / 256, 256, 0, stream>>>(qkv, P, sorted,
                                                           out, N);
}